// Round 12
// baseline (176.471 us; speedup 1.0000x reference)
//
#include <hip/hip_runtime.h>
#include <hip/hip_bf16.h>

#define BB   2048
#define TT   240
#define DD   90
#define MM   (BB*TT)          // 491520
#define KDIM (TT*DD)          // 21600 (original K of out GEMM)
#define KD2  23040            // padded K: 3 panels * 240 t * 32 ddl
#define PSTRIDE ((size_t)MM*32)   // h panel stride (elements)
#define NCLS 40
#define NPAD 48               // k2 N padded to 3 MFMA col-tiles
#define KS2  45               // k2 split-K chunks (45*512 = 23040)
#define KST  16               // k-steps (x32) per chunk

typedef __bf16 bf16x8 __attribute__((ext_vector_type(8)));
typedef float  f32x4  __attribute__((ext_vector_type(4)));

#define LOG2E  1.44269504f
#define LOG2E2 2.88539008f

__device__ __forceinline__ bf16x8 cvt8(float4 a, float4 b){
    bf16x8 r;
    r[0]=(__bf16)a.x; r[1]=(__bf16)a.y; r[2]=(__bf16)a.z; r[3]=(__bf16)a.w;
    r[4]=(__bf16)b.x; r[5]=(__bf16)b.y; r[6]=(__bf16)b.z; r[7]=(__bf16)b.w;
    return r;
}

__device__ __forceinline__ unsigned pack_bf16(float a, float b){
    unsigned u0 = (unsigned)__builtin_bit_cast(unsigned short, (__bf16)a);
    unsigned u1 = (unsigned)__builtin_bit_cast(unsigned short, (__bf16)b);
    return u0 | (u1 << 16);
}

// sigm(a)*tanh(b) = (Eb-1) / ((1+ea)*(Eb+1)),  ea=e^-a, Eb=e^{2b}.
// 2 exp + 1 raw v_rcp per call -- no IEEE-div fixup sequences (r9-verified).
__device__ __forceinline__ float sig_tanh(float a, float b){
    float ea = exp2f(-LOG2E*a);
    float Eb = exp2f(LOG2E2*b);
    return (Eb - 1.f) * __builtin_amdgcn_rcpf((1.f + ea)*(Eb + 1.f));
}

// ---------------------------------------------------------------------------
// pack1: Wtb[c][k] bf16, c = g*96+dd (gates i,g,o), k padded 90->104.
// Bias folded into K: k=90 holds hi(b_ih+b_hh), k=91 holds lo residual;
// x-side fragment supplies 1.0 at k=90,91. k=92..103 zero.
// dd in [90,96): all-zero rows -> pad h columns compute exactly 0.
// ---------------------------------------------------------------------------
__global__ void pack1(const float* __restrict__ Wih,
                      const float* __restrict__ bih,
                      const float* __restrict__ bhh,
                      __bf16* __restrict__ wtb)
{
    int id = blockIdx.x*256 + threadIdx.x;
    if (id >= 288*13) return;
    int c  = id / 13;
    int k8 = id - c*13;
    int g  = c / 96, dd = c - g*96;
    int row = (g==0 ? dd : (g==1 ? 180+dd : 270+dd));
    float bv = 0.f, bhi = 0.f, blo = 0.f;
    if (dd < 90){
        bv  = bih[row] + bhh[row];
        bhi = (float)(__bf16)bv;
        blo = bv - bhi;
    }
    bf16x8 v;
    #pragma unroll
    for (int e = 0; e < 8; ++e){
        int k = k8*8 + e;
        float f = 0.f;
        if (dd < 90){
            if (k < 90)       f = Wih[row*90 + k];
            else if (k == 90) f = bhi;
            else if (k == 91) f = blo;
        }
        v[e] = (__bf16)f;
    }
    *(bf16x8*)(wtb + c*104 + k8*8) = v;
}

// ---------------------------------------------------------------------------
// pack2: hi/lo bf16 split of W_out in PANEL-MAJOR padded-K layout [48][23040]:
// k' = p*7680 + t*32 + ddl, d = p*32 + ddl (d in [90,96) -> zero).
// Matches k1's 3-panel h layout h_p[m][32].
// ---------------------------------------------------------------------------
__global__ void pack2(const float* __restrict__ W2,
                      __bf16* __restrict__ w2hi,
                      __bf16* __restrict__ w2lo)
{
    int id = blockIdx.x*256 + threadIdx.x;
    if (id >= NPAD*(KD2/8)) return;
    int n   = id / (KD2/8);
    int k8  = id - n*(KD2/8);
    int kk  = k8*8;
    int p   = kk / 7680;
    int rem = kk - p*7680;
    int t   = rem / 32;
    int ddl = rem - t*32;             // 0,8,16,24: stays within one 32-block
    bf16x8 vh, vl;
    #pragma unroll
    for (int e = 0; e < 8; ++e){
        int d = p*32 + ddl + e;
        float f = (n < NCLS && d < 90) ? W2[(size_t)n*KDIM + t*90 + d] : 0.f;
        __bf16 hb = (__bf16)f;
        vh[e] = hb;
        vl[e] = (__bf16)(f - (float)hb);
    }
    *(bf16x8*)(w2hi + (size_t)n*KD2 + kk) = vh;
    *(bf16x8*)(w2lo + (size_t)n*KD2 + kk) = vl;
}

// ---------------------------------------------------------------------------
// k1 v12: gates GEMM, ZERO LDS / ZERO barriers. Wave N-slice = 16 cols ->
// W working set = 9 bf16x8 = 36 VGPR, register-resident for all 15 tiles
// (r9-r11 re-read the same W frags from LDS 27x per tile: the lgkmcnt
// stalls behind 58% VALUBusy). Grid (512 m-blocks, 3 col-panels);
// block = 8 waves = 4 row-groups x 2 col-slices. h stored in 3 panels
// h_p[m][32]: each block writes FULL 64B lines of its panel (r8's
// write-amplification trap avoided). x re-read: 2x same-CU (L1), 3x
// across panels (L2/L3-resident). C^T MFMA orientation (r7-verified).
// ---------------------------------------------------------------------------
__global__ __launch_bounds__(512, 2)
void k1_gates(const float* __restrict__ x,
              const __bf16* __restrict__ wtb,
              __bf16* __restrict__ h)
{
    const int tid  = threadIdx.x;
    const int lane = tid & 63;
    const int wv   = tid >> 6;           // 0..7
    const int rg   = wv >> 1;            // row group 0..3
    const int csl  = wv & 1;             // col-slice within panel 0..1
    const int cs   = blockIdx.y*2 + csl; // global 16-col slice 0..5
    const int l15  = lane & 15;
    const int kg   = lane >> 4;          // 0..3

    // loop-invariant W fragments from global (L2-resident, 60KB):
    // row c = g*96 + cs*16 + l15, k = ks*32 + kg*8 + e
    bf16x8 wf[3][3];
    #pragma unroll
    for (int g = 0; g < 3; ++g){
        const __bf16* wp = wtb + (g*96 + cs*16 + l15)*104 + kg*8;
        #pragma unroll
        for (int ks = 0; ks < 3; ++ks)
            wf[g][ks] = *(const bf16x8*)(wp + ks*32);
    }

    const int tbase = blockIdx.x * 15;   // 512 blocks * 15 tiles * 64 rows
    __bf16* hpanel = h + (size_t)blockIdx.y*PSTRIDE;

    // x loads: lane (l15,kg) reads row (rg*16 + l15), k = ks*32 + kg*8 + e
    float4 xr[6];
    float2 xe;
    {
        const float* p = x + ((size_t)tbase*64 + rg*16 + l15)*90;
        #pragma unroll
        for (int ks = 0; ks < 2; ++ks){
            xr[ks*2+0] = *(const float4*)(p + ks*32 + kg*8);
            xr[ks*2+1] = *(const float4*)(p + ks*32 + kg*8 + 4);
        }
        if (kg < 3){
            xr[4] = *(const float4*)(p + 64 + kg*8);
            xr[5] = *(const float4*)(p + 64 + kg*8 + 4);
        } else {
            xe = *(const float2*)(p + 88);
        }
    }

    for (int t = 0; t < 15; ++t){
        // cvt prefetched f32 -> bf16 x-frags (first use waits vmcnt)
        bf16x8 af[3];
        af[0] = cvt8(xr[0], xr[1]);
        af[1] = cvt8(xr[2], xr[3]);
        if (kg < 3){
            af[2] = cvt8(xr[4], xr[5]);
        } else {
            // kg=3 covers k=88..95: x88, x89, then 1.0 at k=90,91 (bias rows)
            bf16x8 z;
            #pragma unroll
            for (int e = 0; e < 8; ++e) z[e] = (__bf16)0.f;
            z[0] = (__bf16)xe.x; z[1] = (__bf16)xe.y;
            z[2] = (__bf16)1.0f; z[3] = (__bf16)1.0f;
            af[2] = z;
        }

        // issue next tile's x loads now; MFMA+epilogue hide the latency
        if (t < 14){
            const float* p = x + ((size_t)(tbase+t+1)*64 + rg*16 + l15)*90;
            #pragma unroll
            for (int ks = 0; ks < 2; ++ks){
                xr[ks*2+0] = *(const float4*)(p + ks*32 + kg*8);
                xr[ks*2+1] = *(const float4*)(p + ks*32 + kg*8 + 4);
            }
            if (kg < 3){
                xr[4] = *(const float4*)(p + 64 + kg*8);
                xr[5] = *(const float4*)(p + 64 + kg*8 + 4);
            } else {
                xe = *(const float2*)(p + 88);
            }
        }

        // 9 MFMAs, all operands in registers. mfma(W, x, acc) -> C^T:
        // lane l15 = m-row, acc[r] -> dd_local = kg*4 + r of this cs-slice.
        f32x4 acc0 = {0.f,0.f,0.f,0.f}, acc1 = acc0, acc2 = acc0;
        #pragma unroll
        for (int ks = 0; ks < 3; ++ks){
            acc0 = __builtin_amdgcn_mfma_f32_16x16x32_bf16(wf[0][ks], af[ks], acc0, 0,0,0);
            acc1 = __builtin_amdgcn_mfma_f32_16x16x32_bf16(wf[1][ks], af[ks], acc1, 0,0,0);
            acc2 = __builtin_amdgcn_mfma_f32_16x16x32_bf16(wf[2][ks], af[ks], acc2, 0,0,0);
        }

        // epilogue: 4 h at panel-cols csl*16 + kg*4 + r (pad cols -> exact 0)
        float hv[4];
        #pragma unroll
        for (int r = 0; r < 4; ++r){
            float cc = sig_tanh(acc0[r], acc1[r]);   // sigm(i)*tanh(g)
            hv[r]    = sig_tanh(acc2[r], cc);        // sigm(o)*tanh(c)
        }
        const size_t mrow = (size_t)(tbase+t)*64 + rg*16 + l15;
        uint2 pk;
        pk.x = pack_bf16(hv[0], hv[1]);
        pk.y = pack_bf16(hv[2], hv[3]);
        *(uint2*)(hpanel + mrow*32 + csl*16 + kg*4) = pk;   // 8B-aligned
    }
}

// ---------------------------------------------------------------------------
// k2: out GEMM [2048 x 23040pad] @ [23040 x 48] via MFMA, split-K 45.
// K order is panel-major: chunk c -> panel p = c/15, t0 = (c%15)*16;
// h addr(b, s) = p*PSTRIDE + (b*240 + t0 + s)*32. W2 packed to match.
// ---------------------------------------------------------------------------
__global__ __launch_bounds__(256)
void k2_out(const __bf16* __restrict__ h,
            const __bf16* __restrict__ w2hi,
            const __bf16* __restrict__ w2lo,
            float* __restrict__ part2)
{
    const int tid  = threadIdx.x;
    const int lane = tid & 63;
    const int wv   = tid >> 6;
    const int l15  = lane & 15;
    const int kg   = lane >> 4;
    const int m0   = (blockIdx.x*4 + wv) * 32;       // 0..2016
    const int chunk= blockIdx.y;                     // 0..44
    const int p    = chunk / 15;
    const int t0   = (chunk - p*15) * 16;

    const __bf16* ha = h + (size_t)p*PSTRIDE
                         + ((size_t)(m0 + l15)*240 + t0)*32 + 8*kg;
    const __bf16* hb = ha + (size_t)16*240*32;
    const size_t kbase = (size_t)chunk*(KST*32) + 8*kg;
    const __bf16* h0 = w2hi + (size_t)l15*KD2 + kbase;
    const __bf16* h1 = h0   + (size_t)16*KD2;
    const __bf16* h2 = h0   + (size_t)32*KD2;
    const __bf16* l0 = w2lo + (size_t)l15*KD2 + kbase;
    const __bf16* l1 = l0   + (size_t)16*KD2;
    const __bf16* l2 = l0   + (size_t)32*KD2;

    f32x4 acc00 = {0.f,0.f,0.f,0.f}, acc01 = acc00, acc02 = acc00;
    f32x4 acc10 = acc00, acc11 = acc00, acc12 = acc00;

    #pragma unroll
    for (int s = 0; s < KST; ++s){
        bf16x8 a0  = *(const bf16x8*)(ha + s*32);
        bf16x8 a1  = *(const bf16x8*)(hb + s*32);
        bf16x8 bh0 = *(const bf16x8*)(h0 + s*32);
        bf16x8 bh1 = *(const bf16x8*)(h1 + s*32);
        bf16x8 bh2 = *(const bf16x8*)(h2 + s*32);
        bf16x8 bl0 = *(const bf16x8*)(l0 + s*32);
        bf16x8 bl1 = *(const bf16x8*)(l1 + s*32);
        bf16x8 bl2 = *(const bf16x8*)(l2 + s*32);
        acc00 = __builtin_amdgcn_mfma_f32_16x16x32_bf16(a0, bh0, acc00, 0,0,0);
        acc01 = __builtin_amdgcn_mfma_f32_16x16x32_bf16(a0, bh1, acc01, 0,0,0);
        acc02 = __builtin_amdgcn_mfma_f32_16x16x32_bf16(a0, bh2, acc02, 0,0,0);
        acc10 = __builtin_amdgcn_mfma_f32_16x16x32_bf16(a1, bh0, acc10, 0,0,0);
        acc11 = __builtin_amdgcn_mfma_f32_16x16x32_bf16(a1, bh1, acc11, 0,0,0);
        acc12 = __builtin_amdgcn_mfma_f32_16x16x32_bf16(a1, bh2, acc12, 0,0,0);
        acc00 = __builtin_amdgcn_mfma_f32_16x16x32_bf16(a0, bl0, acc00, 0,0,0);
        acc01 = __builtin_amdgcn_mfma_f32_16x16x32_bf16(a0, bl1, acc01, 0,0,0);
        acc02 = __builtin_amdgcn_mfma_f32_16x16x32_bf16(a0, bl2, acc02, 0,0,0);
        acc10 = __builtin_amdgcn_mfma_f32_16x16x32_bf16(a1, bl0, acc10, 0,0,0);
        acc11 = __builtin_amdgcn_mfma_f32_16x16x32_bf16(a1, bl1, acc11, 0,0,0);
        acc12 = __builtin_amdgcn_mfma_f32_16x16x32_bf16(a1, bl2, acc12, 0,0,0);
    }

    float* pp = part2 + (size_t)chunk*(BB*NPAD);
    const int rbase = kg*4;
    #pragma unroll
    for (int r = 0; r < 4; ++r){
        size_t row0 = (size_t)(m0 + rbase + r)*NPAD;
        size_t row1 = (size_t)(m0 + 16 + rbase + r)*NPAD;
        pp[row0 +      l15] = acc00[r];
        pp[row0 + 16 + l15] = acc01[r];
        pp[row0 + 32 + l15] = acc02[r];
        pp[row1 +      l15] = acc10[r];
        pp[row1 + 16 + l15] = acc11[r];
        pp[row1 + 32 + l15] = acc12[r];
    }
}

// ---------------------------------------------------------------------------
// k3 (fused): reduce split-K partials + bias, then softmax over groups of 10.
// 256 blocks x 384 thr = 8 b-rows x 48 n each; LDS handoff to 32 threads.
// ---------------------------------------------------------------------------
__global__ __launch_bounds__(384)
void k3(const float* __restrict__ part2,
        const float* __restrict__ bout,
        float* __restrict__ out)
{
    __shared__ float sm[8*NPAD];
    const int tid  = threadIdx.x;
    const int base = blockIdx.x * 8 * NPAD;      // flat (b*48+n) base

    {
        int g = base + tid;
        float s = 0.f;
        for (int c = 0; c < KS2; ++c) s += part2[(size_t)c*(BB*NPAD) + g];
        int n = tid % NPAD;
        sm[tid] = s + (n < NCLS ? bout[n] : 0.f);
    }
    __syncthreads();

    if (tid < 32){
        int lb  = tid >> 2;      // 0..7
        int grp = tid & 3;       // 0..3
        const float* lg = sm + lb*NPAD + grp*10;
        float v[10]; float mx = -1e30f;
        #pragma unroll
        for (int q = 0; q < 10; ++q){ v[q] = lg[q]; mx = fmaxf(mx, v[q]); }
        float e[10]; float s = 0.f;
        #pragma unroll
        for (int q = 0; q < 10; ++q){ e[q] = __expf(v[q]-mx); s += e[q]; }
        float inv = 1.0f/s;
        size_t b = (size_t)blockIdx.x*8 + lb;
        #pragma unroll
        for (int q = 0; q < 10; ++q) out[b*NCLS + grp*10 + q] = e[q]*inv;
    }
}

// ---------------------------------------------------------------------------
extern "C" void kernel_launch(void* const* d_in, const int* in_sizes, int n_in,
                              void* d_out, int out_size, void* d_ws, size_t ws_size,
                              hipStream_t stream)
{
    const float* x    = (const float*)d_in[0];
    const float* Wih  = (const float*)d_in[1];
    // d_in[2] = W_hh unused (zero initial hidden state)
    const float* bih  = (const float*)d_in[3];
    const float* bhh  = (const float*)d_in[4];
    const float* W2   = (const float*)d_in[5];
    const float* bout = (const float*)d_in[6];
    float* out = (float*)d_out;

    char* ws = (char*)d_ws;
    size_t off = 0;
    auto alloc = [&](size_t bytes){ void* p = ws + off; off = (off + bytes + 255) & ~(size_t)255; return p; };
    __bf16* h     = (__bf16*)alloc((size_t)3*PSTRIDE*2);       // 94.4 MB (3 panels)
    float*  part2 = (float*) alloc((size_t)KS2*BB*NPAD*4);     // 17.7 MB
    __bf16* wtb   = (__bf16*)alloc(288*104*2);                 // 60 KB
    __bf16* w2hi  = (__bf16*)alloc((size_t)NPAD*KD2*2);        // 2.2 MB
    __bf16* w2lo  = (__bf16*)alloc((size_t)NPAD*KD2*2);        // 2.2 MB

    pack1<<<15, 256, 0, stream>>>(Wih, bih, bhh, wtb);
    pack2<<<(NPAD*(KD2/8) + 255)/256, 256, 0, stream>>>(W2, w2hi, w2lo);
    k1_gates<<<dim3(512, 3), 512, 0, stream>>>(x, wtb, h);
    k2_out<<<dim3(16, KS2), 256, 0, stream>>>(h, w2hi, w2lo, part2);
    k3<<<BB/8, 384, 0, stream>>>(part2, bout, out);
}